// Round 1
// baseline (1257.154 us; speedup 1.0000x reference)
//
#include <hip/hip_runtime.h>
#include <math.h>

#define M 128
#define TOPK 32
#define NVAL 32768
#define D 4096

// ---------------- GEMM: C[M=128 x N] = A[128 x K] @ B[N x K]^T ----------------
// Block computes a [128 x 128] tile over a K-range (grid.y = K-split index).
__global__ __launch_bounds__(256) void gemm_kernel(
    const float* __restrict__ A, const float* __restrict__ B,
    float* __restrict__ C, int K, int N, int klen)
{
    __shared__ float a_t[32][132];
    __shared__ float b_t[32][132];
    const int t = threadIdx.x;
    const int ntile = blockIdx.x * 128;
    const int k0 = blockIdx.y * klen;
    float* Cb = C + (size_t)blockIdx.y * M * N;
    const int m0 = (t >> 4) * 8;
    const int n0 = (t & 15) * 8;
    float acc[8][8] = {};

    for (int ks = k0; ks < k0 + klen; ks += 32) {
        #pragma unroll
        for (int j = 0; j < 4; ++j) {
            int c = t + 256 * j;           // 0..1023
            int row = c >> 3, kq = c & 7;  // row 0..127, kq 0..7
            const float4 va = *(const float4*)(A + (size_t)row * K + ks + kq * 4);
            a_t[kq*4+0][row] = va.x; a_t[kq*4+1][row] = va.y;
            a_t[kq*4+2][row] = va.z; a_t[kq*4+3][row] = va.w;
            const float4 vb = *(const float4*)(B + (size_t)(ntile + row) * K + ks + kq * 4);
            b_t[kq*4+0][row] = vb.x; b_t[kq*4+1][row] = vb.y;
            b_t[kq*4+2][row] = vb.z; b_t[kq*4+3][row] = vb.w;
        }
        __syncthreads();
        #pragma unroll 2
        for (int kk = 0; kk < 32; ++kk) {
            float4 a0 = *(const float4*)&a_t[kk][m0];
            float4 a1 = *(const float4*)&a_t[kk][m0 + 4];
            float4 b0 = *(const float4*)&b_t[kk][n0];
            float4 b1 = *(const float4*)&b_t[kk][n0 + 4];
            float av[8] = {a0.x,a0.y,a0.z,a0.w,a1.x,a1.y,a1.z,a1.w};
            float bv[8] = {b0.x,b0.y,b0.z,b0.w,b1.x,b1.y,b1.z,b1.w};
            #pragma unroll
            for (int i = 0; i < 8; ++i)
                #pragma unroll
                for (int j = 0; j < 8; ++j)
                    acc[i][j] = fmaf(av[i], bv[j], acc[i][j]);
        }
        __syncthreads();
    }
    #pragma unroll
    for (int i = 0; i < 8; ++i) {
        float4 o0 = {acc[i][0], acc[i][1], acc[i][2], acc[i][3]};
        float4 o1 = {acc[i][4], acc[i][5], acc[i][6], acc[i][7]};
        *(float4*)(Cb + (size_t)(m0 + i) * N + ntile + n0)     = o0;
        *(float4*)(Cb + (size_t)(m0 + i) * N + ntile + n0 + 4) = o1;
    }
}

// ------------- reduce 8 K-split partials [8][128*N] -> [128*N] -------------
__global__ __launch_bounds__(256) void reduce8_kernel(
    const float* __restrict__ part, float* __restrict__ out, int elems4)
{
    int i = blockIdx.x * blockDim.x + threadIdx.x;
    if (i < elems4) {
        float4 s = {0.f, 0.f, 0.f, 0.f};
        #pragma unroll
        for (int r = 0; r < 8; ++r) {
            float4 v = *(const float4*)(part + (size_t)r * elems4 * 4 + (size_t)i * 4);
            s.x += v.x; s.y += v.y; s.z += v.z; s.w += v.w;
        }
        *(float4*)(out + (size_t)i * 4) = s;
    }
}

// ------------- iterative top-32 per row; mutates scores in place -------------
__global__ __launch_bounds__(256) void topk_kernel(
    float* __restrict__ scores, int n, int* __restrict__ idx_out)
{
    __shared__ float rv[256];
    __shared__ int   ri[256];
    const int t = threadIdx.x;
    float* row = scores + (size_t)blockIdx.x * n;
    int* out = idx_out + blockIdx.x * TOPK;
    const int cnt = n >> 8;
    for (int sel = 0; sel < TOPK; ++sel) {
        float bv = -INFINITY; int bi = n;
        for (int i = 0; i < cnt; ++i) {
            int idx = t + (i << 8);
            float v = row[idx];
            if (v > bv || (v == bv && idx < bi)) { bv = v; bi = idx; }
        }
        rv[t] = bv; ri[t] = bi;
        __syncthreads();
        for (int s = 128; s > 0; s >>= 1) {
            if (t < s) {
                float ov = rv[t + s]; int oi = ri[t + s];
                if (ov > rv[t] || (ov == rv[t] && oi < ri[t])) { rv[t] = ov; ri[t] = oi; }
            }
            __syncthreads();
        }
        if (t == 0) {
            out[sel] = ri[0];
            row[ri[0]] = -INFINITY;
        }
        __syncthreads();
    }
}

// ---- gather 32 rows of clique_encoder [.,4096], sum, scale, l2-normalize ----
__global__ __launch_bounds__(256) void gather_norm_kernel(
    const float* __restrict__ enc, const int* __restrict__ idx, float* __restrict__ p)
{
    __shared__ int rows[TOPK];
    __shared__ float red[256];
    const int t = threadIdx.x;
    const int b = blockIdx.x;
    if (t < TOPK) rows[t] = idx[b * TOPK + t];
    __syncthreads();
    float4 acc[4] = {};
    for (int r = 0; r < TOPK; ++r) {
        const float* src = enc + (size_t)rows[r] * D + t * 16;
        #pragma unroll
        for (int q = 0; q < 4; ++q) {
            float4 v = *(const float4*)(src + q * 4);
            acc[q].x += v.x; acc[q].y += v.y; acc[q].z += v.z; acc[q].w += v.w;
        }
    }
    const float sc = 0.17677669529663687f; // 1/sqrt(32)
    float ss = 0.f;
    #pragma unroll
    for (int q = 0; q < 4; ++q) {
        acc[q].x *= sc; acc[q].y *= sc; acc[q].z *= sc; acc[q].w *= sc;
        ss += acc[q].x*acc[q].x + acc[q].y*acc[q].y + acc[q].z*acc[q].z + acc[q].w*acc[q].w;
    }
    red[t] = ss;
    __syncthreads();
    for (int s = 128; s > 0; s >>= 1) {
        if (t < s) red[t] += red[t + s];
        __syncthreads();
    }
    float rinv = 1.0f / fmaxf(sqrtf(red[0]), 1e-12f);
    float* dst = p + (size_t)b * D + t * 16;
    #pragma unroll
    for (int q = 0; q < 4; ++q) {
        float4 o = {acc[q].x*rinv, acc[q].y*rinv, acc[q].z*rinv, acc[q].w*rinv};
        *(float4*)(dst + q * 4) = o;
    }
}

// -------- gather 32 rows of assoc_mem_value [.,32768], sum -> out --------
__global__ __launch_bounds__(256) void gather_out_kernel(
    const float* __restrict__ mem, const int* __restrict__ idx, float* __restrict__ out)
{
    __shared__ int rows[TOPK];
    const int t = threadIdx.x;
    const int b = blockIdx.y;      // key row
    const int chunk = blockIdx.x;  // 0..15
    if (t < TOPK) rows[t] = idx[b * TOPK + t];
    __syncthreads();
    const int off = chunk * 2048 + t * 8;
    float4 a0 = {}, a1 = {};
    for (int r = 0; r < TOPK; ++r) {
        const float* src = mem + (size_t)rows[r] * NVAL + off;
        float4 v0 = *(const float4*)(src);
        float4 v1 = *(const float4*)(src + 4);
        a0.x += v0.x; a0.y += v0.y; a0.z += v0.z; a0.w += v0.w;
        a1.x += v1.x; a1.y += v1.y; a1.z += v1.z; a1.w += v1.w;
    }
    float* dst = out + (size_t)b * NVAL + off;
    *(float4*)dst = a0;
    *(float4*)(dst + 4) = a1;
}

extern "C" void kernel_launch(void* const* d_in, const int* in_sizes, int n_in,
                              void* d_out, int out_size, void* d_ws, size_t ws_size,
                              hipStream_t stream) {
    const float* keys            = (const float*)d_in[0];
    const float* value_proj      = (const float*)d_in[1];
    const float* clique_encoder  = (const float*)d_in[2];
    const float* assoc_proj      = (const float*)d_in[3];
    const float* assoc_mem_value = (const float*)d_in[4];
    float* out = (float*)d_out;

    char* ws = (char*)d_ws;
    float* scores1  = (float*)(ws);                    // 128*32768*4 = 16777216
    float* p        = (float*)(ws + 16777216);         // 128*4096*4  =  2097152
    float* partials = (float*)(ws + 18874368);         // 8*128*4096*4 = 16777216
    float* scores2  = (float*)(ws + 35651584);         // 128*4096*4  =  2097152
    int*   idx1     = (int*)  (ws + 37748736);         // 16384
    int*   idx2     = (int*)  (ws + 37765120);         // 16384

    // 1) scores1 = keys @ value_proj^T   (M=128,N=32768,K=1024)
    gemm_kernel<<<dim3(256, 1), 256, 0, stream>>>(keys, value_proj, scores1, 1024, 32768, 1024);
    // 2) top-32 per row
    topk_kernel<<<128, 256, 0, stream>>>(scores1, 32768, idx1);
    // 3) p = normalize(sum(clique_encoder[idx1]) / sqrt(32))
    gather_norm_kernel<<<128, 256, 0, stream>>>(clique_encoder, idx1, p);
    // 4) scores2 = p @ assoc_proj^T  (M=128,N=4096,K=4096), 8-way K-split partials
    gemm_kernel<<<dim3(32, 8), 256, 0, stream>>>(p, assoc_proj, partials, 4096, 4096, 512);
    // 5) reduce partials
    reduce8_kernel<<<512, 256, 0, stream>>>(partials, scores2, 131072);
    // 6) top-32 per row
    topk_kernel<<<128, 256, 0, stream>>>(scores2, 4096, idx2);
    // 7) out = sum(assoc_mem_value[idx2])
    gather_out_kernel<<<dim3(16, 128), 256, 0, stream>>>(assoc_mem_value, idx2, out);
}

// Round 2
// 600.767 us; speedup vs baseline: 2.0926x; 2.0926x over previous
//
#include <hip/hip_runtime.h>
#include <math.h>

#define M 128
#define TOPK 32
#define NVAL 32768
#define D 4096

// ---------------- GEMM: C[M=128 x N] = A[128 x K] @ B[N x K]^T ----------------
// Block computes a [128 x 128] tile over a K-range (grid.y = K-split index).
__global__ __launch_bounds__(256) void gemm_kernel(
    const float* __restrict__ A, const float* __restrict__ B,
    float* __restrict__ C, int K, int N, int klen)
{
    __shared__ float a_t[32][132];
    __shared__ float b_t[32][132];
    const int t = threadIdx.x;
    const int ntile = blockIdx.x * 128;
    const int k0 = blockIdx.y * klen;
    float* Cb = C + (size_t)blockIdx.y * M * N;
    const int m0 = (t >> 4) * 8;
    const int n0 = (t & 15) * 8;
    float acc[8][8] = {};

    for (int ks = k0; ks < k0 + klen; ks += 32) {
        #pragma unroll
        for (int j = 0; j < 4; ++j) {
            int c = t + 256 * j;           // 0..1023
            int row = c >> 3, kq = c & 7;  // row 0..127, kq 0..7
            const float4 va = *(const float4*)(A + (size_t)row * K + ks + kq * 4);
            a_t[kq*4+0][row] = va.x; a_t[kq*4+1][row] = va.y;
            a_t[kq*4+2][row] = va.z; a_t[kq*4+3][row] = va.w;
            const float4 vb = *(const float4*)(B + (size_t)(ntile + row) * K + ks + kq * 4);
            b_t[kq*4+0][row] = vb.x; b_t[kq*4+1][row] = vb.y;
            b_t[kq*4+2][row] = vb.z; b_t[kq*4+3][row] = vb.w;
        }
        __syncthreads();
        #pragma unroll 2
        for (int kk = 0; kk < 32; ++kk) {
            float4 a0 = *(const float4*)&a_t[kk][m0];
            float4 a1 = *(const float4*)&a_t[kk][m0 + 4];
            float4 b0 = *(const float4*)&b_t[kk][n0];
            float4 b1 = *(const float4*)&b_t[kk][n0 + 4];
            float av[8] = {a0.x,a0.y,a0.z,a0.w,a1.x,a1.y,a1.z,a1.w};
            float bv[8] = {b0.x,b0.y,b0.z,b0.w,b1.x,b1.y,b1.z,b1.w};
            #pragma unroll
            for (int i = 0; i < 8; ++i)
                #pragma unroll
                for (int j = 0; j < 8; ++j)
                    acc[i][j] = fmaf(av[i], bv[j], acc[i][j]);
        }
        __syncthreads();
    }
    #pragma unroll
    for (int i = 0; i < 8; ++i) {
        float4 o0 = {acc[i][0], acc[i][1], acc[i][2], acc[i][3]};
        float4 o1 = {acc[i][4], acc[i][5], acc[i][6], acc[i][7]};
        *(float4*)(Cb + (size_t)(m0 + i) * N + ntile + n0)     = o0;
        *(float4*)(Cb + (size_t)(m0 + i) * N + ntile + n0 + 4) = o1;
    }
}

// ------------- reduce 8 K-split partials [8][128*N] -> [128*N] -------------
__global__ __launch_bounds__(256) void reduce8_kernel(
    const float* __restrict__ part, float* __restrict__ out, int elems4)
{
    int i = blockIdx.x * blockDim.x + threadIdx.x;
    if (i < elems4) {
        float4 s = {0.f, 0.f, 0.f, 0.f};
        #pragma unroll
        for (int r = 0; r < 8; ++r) {
            float4 v = *(const float4*)(part + (size_t)r * elems4 * 4 + (size_t)i * 4);
            s.x += v.x; s.y += v.y; s.z += v.z; s.w += v.w;
        }
        *(float4*)(out + (size_t)i * 4) = s;
    }
}

// ------------- single-pass top-32 per row -------------
// Packed sortable key: (sortable_float_bits << 32) | ~idx
//   -> unsigned compare == (value desc, index asc), jax.lax.top_k tie semantics.
#define NT 512
__global__ __launch_bounds__(NT) void topk_kernel(
    const float* __restrict__ scores, int n, int* __restrict__ idx_out)
{
    __shared__ unsigned long long lkey[NT * 32];   // 128 KB
    __shared__ unsigned long long wkey[NT / 64];
    const int t = threadIdx.x;
    const float* row = scores + (size_t)blockIdx.x * n;

    unsigned long long kl[32];
    #pragma unroll
    for (int i = 0; i < 32; ++i) kl[i] = 0ull;   // below any real score

    const int nvec = n >> 2;
    for (int base = t; base < nvec; base += NT) {
        float4 x4 = *(const float4*)(row + base * 4);
        float xs[4] = {x4.x, x4.y, x4.z, x4.w};
        #pragma unroll
        for (int q = 0; q < 4; ++q) {
            unsigned int fb = __float_as_uint(xs[q]);
            unsigned int s = (fb & 0x80000000u) ? ~fb : (fb | 0x80000000u);
            unsigned int idx = (unsigned int)(base * 4 + q);
            unsigned long long key = ((unsigned long long)s << 32) | (unsigned long long)(~idx);
            if (key > kl[31]) {
                unsigned long long c = key;
                #pragma unroll
                for (int i = 0; i < 32; ++i) {
                    unsigned long long old = kl[i];
                    bool gt = c > old;
                    kl[i] = gt ? c : old;
                    c = gt ? old : c;
                }
            }
        }
    }
    #pragma unroll
    for (int i = 0; i < 32; ++i) lkey[i * NT + t] = kl[i];  // [pos][thread]: conflict-free
    __syncthreads();

    int h = 0;
    int* out = idx_out + blockIdx.x * TOPK;
    for (int sel = 0; sel < TOPK; ++sel) {
        unsigned long long cand = (h < 32) ? lkey[h * NT + t] : 0ull;
        unsigned long long b = cand;
        #pragma unroll
        for (int s = 1; s < 64; s <<= 1) {
            unsigned long long o = __shfl_xor(b, s);
            if (o > b) b = o;
        }
        if ((t & 63) == 0) wkey[t >> 6] = b;
        __syncthreads();
        unsigned long long g = wkey[0];
        #pragma unroll
        for (int w = 1; w < NT / 64; ++w) {
            unsigned long long o = wkey[w];
            if (o > g) g = o;
        }
        if (t == 0) out[sel] = (int)(~(unsigned int)g);
        if (cand == g) h++;   // index bits make keys unique; only winner advances
        __syncthreads();
    }
}

// ---- gather 32 rows of clique_encoder [.,4096], sum, scale, l2-normalize ----
__global__ __launch_bounds__(256) void gather_norm_kernel(
    const float* __restrict__ enc, const int* __restrict__ idx, float* __restrict__ p)
{
    __shared__ int rows[TOPK];
    __shared__ float red[256];
    const int t = threadIdx.x;
    const int b = blockIdx.x;
    if (t < TOPK) rows[t] = idx[b * TOPK + t];
    __syncthreads();
    float4 acc[4] = {};
    for (int r = 0; r < TOPK; ++r) {
        const float* src = enc + (size_t)rows[r] * D + t * 16;
        #pragma unroll
        for (int q = 0; q < 4; ++q) {
            float4 v = *(const float4*)(src + q * 4);
            acc[q].x += v.x; acc[q].y += v.y; acc[q].z += v.z; acc[q].w += v.w;
        }
    }
    const float sc = 0.17677669529663687f; // 1/sqrt(32)
    float ss = 0.f;
    #pragma unroll
    for (int q = 0; q < 4; ++q) {
        acc[q].x *= sc; acc[q].y *= sc; acc[q].z *= sc; acc[q].w *= sc;
        ss += acc[q].x*acc[q].x + acc[q].y*acc[q].y + acc[q].z*acc[q].z + acc[q].w*acc[q].w;
    }
    red[t] = ss;
    __syncthreads();
    for (int s = 128; s > 0; s >>= 1) {
        if (t < s) red[t] += red[t + s];
        __syncthreads();
    }
    float rinv = 1.0f / fmaxf(sqrtf(red[0]), 1e-12f);
    float* dst = p + (size_t)b * D + t * 16;
    #pragma unroll
    for (int q = 0; q < 4; ++q) {
        float4 o = {acc[q].x*rinv, acc[q].y*rinv, acc[q].z*rinv, acc[q].w*rinv};
        *(float4*)(dst + q * 4) = o;
    }
}

// -------- gather 32 rows of assoc_mem_value [.,32768], sum -> out --------
__global__ __launch_bounds__(256) void gather_out_kernel(
    const float* __restrict__ mem, const int* __restrict__ idx, float* __restrict__ out)
{
    __shared__ int rows[TOPK];
    const int t = threadIdx.x;
    const int b = blockIdx.y;      // key row
    const int chunk = blockIdx.x;  // 0..15
    if (t < TOPK) rows[t] = idx[b * TOPK + t];
    __syncthreads();
    const int off = chunk * 2048 + t * 8;
    float4 a0 = {}, a1 = {};
    for (int r = 0; r < TOPK; ++r) {
        const float* src = mem + (size_t)rows[r] * NVAL + off;
        float4 v0 = *(const float4*)(src);
        float4 v1 = *(const float4*)(src + 4);
        a0.x += v0.x; a0.y += v0.y; a0.z += v0.z; a0.w += v0.w;
        a1.x += v1.x; a1.y += v1.y; a1.z += v1.z; a1.w += v1.w;
    }
    float* dst = out + (size_t)b * NVAL + off;
    *(float4*)dst = a0;
    *(float4*)(dst + 4) = a1;
}

extern "C" void kernel_launch(void* const* d_in, const int* in_sizes, int n_in,
                              void* d_out, int out_size, void* d_ws, size_t ws_size,
                              hipStream_t stream) {
    const float* keys            = (const float*)d_in[0];
    const float* value_proj      = (const float*)d_in[1];
    const float* clique_encoder  = (const float*)d_in[2];
    const float* assoc_proj      = (const float*)d_in[3];
    const float* assoc_mem_value = (const float*)d_in[4];
    float* out = (float*)d_out;

    char* ws = (char*)d_ws;
    float* scores1  = (float*)(ws);                    // 128*32768*4 = 16777216
    float* p        = (float*)(ws + 16777216);         // 128*4096*4  =  2097152
    float* partials = (float*)(ws + 18874368);         // 8*128*4096*4 = 16777216
    float* scores2  = (float*)(ws + 35651584);         // 128*4096*4  =  2097152
    int*   idx1     = (int*)  (ws + 37748736);         // 16384
    int*   idx2     = (int*)  (ws + 37765120);         // 16384

    // 1) scores1 = keys @ value_proj^T   (M=128,N=32768,K=1024)
    gemm_kernel<<<dim3(256, 1), 256, 0, stream>>>(keys, value_proj, scores1, 1024, 32768, 1024);
    // 2) top-32 per row (single pass)
    topk_kernel<<<128, NT, 0, stream>>>(scores1, 32768, idx1);
    // 3) p = normalize(sum(clique_encoder[idx1]) / sqrt(32))
    gather_norm_kernel<<<128, 256, 0, stream>>>(clique_encoder, idx1, p);
    // 4) scores2 = p @ assoc_proj^T  (M=128,N=4096,K=4096), 8-way K-split partials
    gemm_kernel<<<dim3(32, 8), 256, 0, stream>>>(p, assoc_proj, partials, 4096, 4096, 512);
    // 5) reduce partials
    reduce8_kernel<<<512, 256, 0, stream>>>(partials, scores2, 131072);
    // 6) top-32 per row (single pass)
    topk_kernel<<<128, NT, 0, stream>>>(scores2, 4096, idx2);
    // 7) out = sum(assoc_mem_value[idx2])
    gather_out_kernel<<<dim3(16, 128), 256, 0, stream>>>(assoc_mem_value, idx2, out);
}

// Round 3
// 531.089 us; speedup vs baseline: 2.3671x; 1.1312x over previous
//
#include <hip/hip_runtime.h>
#include <math.h>

#define TOPK 32
#define NVAL 32768
#define D 4096

typedef __attribute__((ext_vector_type(8))) short bf16x8;
typedef __attribute__((ext_vector_type(4))) float f32x4;

__device__ inline short f2bf(float x) {
    union { float f; unsigned u; } v; v.f = x;
    unsigned r = v.u + 0x7fffu + ((v.u >> 16) & 1u);  // RNE
    return (short)(r >> 16);
}

// ---------------- fp32 -> bf16 streaming convert ----------------
__global__ __launch_bounds__(256) void cvt_bf16_kernel(
    const float* __restrict__ in, short* __restrict__ out, int n4)
{
    int i = blockIdx.x * 256 + threadIdx.x;
    if (i < n4) {
        float4 v = ((const float4*)in)[i];
        short4 o = {f2bf(v.x), f2bf(v.y), f2bf(v.z), f2bf(v.w)};
        ((short4*)out)[i] = o;
    }
}

// ------- approx GEMM: C[128 x N] = A[128 x K](bf16) @ B[N x K](fp32->bf16)^T -------
// grid.x: N/64 (4 waves x 16 B-rows), grid.y: K-split. MFMA 16x16x32 bf16.
__global__ __launch_bounds__(256) void gemm_bf16_kernel(
    const short* __restrict__ Abf, const float* __restrict__ B,
    float* __restrict__ C, int K, int N, int klen)
{
    const int t = threadIdx.x;
    const int lane = t & 63;
    const int w = t >> 6;
    const int ntile = blockIdx.x * 64 + w * 16;
    const int k0 = blockIdx.y * klen;
    float* Cb = C + (size_t)blockIdx.y * 128 * N;

    const int kfrag = (lane >> 4) * 8;
    const float* bp = B + (size_t)(ntile + (lane & 15)) * K + kfrag;
    const short* ap = Abf + (size_t)(lane & 15) * K + kfrag;

    f32x4 acc[8];
    #pragma unroll
    for (int j = 0; j < 8; ++j) acc[j] = (f32x4){0.f, 0.f, 0.f, 0.f};

    float4 pv0 = *(const float4*)(bp + k0);
    float4 pv1 = *(const float4*)(bp + k0 + 4);
    for (int ks = k0; ks < k0 + klen; ks += 32) {
        float4 c0 = pv0, c1 = pv1;
        if (ks + 32 < k0 + klen) {
            pv0 = *(const float4*)(bp + ks + 32);
            pv1 = *(const float4*)(bp + ks + 36);
        }
        bf16x8 af;
        af[0] = f2bf(c0.x); af[1] = f2bf(c0.y); af[2] = f2bf(c0.z); af[3] = f2bf(c0.w);
        af[4] = f2bf(c1.x); af[5] = f2bf(c1.y); af[6] = f2bf(c1.z); af[7] = f2bf(c1.w);
        #pragma unroll
        for (int j = 0; j < 8; ++j) {
            bf16x8 kf = *(const bf16x8*)(ap + (size_t)16 * K * j + ks);
            acc[j] = __builtin_amdgcn_mfma_f32_16x16x32_bf16(af, kf, acc[j], 0, 0, 0);
        }
    }
    // D: col(lane&15) = keys-row within m-tile, row((lane>>4)*4+r) = vproj-row offset
    const int crow0 = ntile + (lane >> 4) * 4;
    const int ccol = lane & 15;
    #pragma unroll
    for (int j = 0; j < 8; ++j) {
        float4 o = {acc[j][0], acc[j][1], acc[j][2], acc[j][3]};
        *(float4*)(Cb + (size_t)(16 * j + ccol) * N + crow0) = o;
    }
}

// ------------- reduce S K-split partials -> out -------------
__global__ __launch_bounds__(256) void reduceS_kernel(
    const float* __restrict__ part, float* __restrict__ out, int elems4, int S)
{
    int i = blockIdx.x * blockDim.x + threadIdx.x;
    if (i < elems4) {
        float4 s = {0.f, 0.f, 0.f, 0.f};
        for (int r = 0; r < S; ++r) {
            float4 v = *(const float4*)(part + (size_t)r * elems4 * 4 + (size_t)i * 4);
            s.x += v.x; s.y += v.y; s.z += v.z; s.w += v.w;
        }
        *(float4*)(out + (size_t)i * 4) = s;
    }
}

// ------------- top-64 candidate filter per row -------------
// key = (sortable_float_bits << 32) | ~idx  (value desc, index asc)
#define FNT 512
__global__ __launch_bounds__(FNT) void filter64_kernel(
    const float* __restrict__ scores, int n, int* __restrict__ cand_out)
{
    __shared__ unsigned long long lkey[8 * FNT];   // 32 KB
    __shared__ unsigned long long wkey[FNT / 64];
    const int t = threadIdx.x;
    const float* row = scores + (size_t)blockIdx.x * n;

    unsigned long long kl[8];
    #pragma unroll
    for (int i = 0; i < 8; ++i) kl[i] = 0ull;

    const int nvec = n >> 2;
    for (int base = t; base < nvec; base += FNT) {
        float4 x4 = *(const float4*)(row + base * 4);
        float xs[4] = {x4.x, x4.y, x4.z, x4.w};
        #pragma unroll
        for (int q = 0; q < 4; ++q) {
            unsigned fb = __float_as_uint(xs[q]);
            unsigned s = (fb & 0x80000000u) ? ~fb : (fb | 0x80000000u);
            unsigned idx = (unsigned)(base * 4 + q);
            unsigned long long key = ((unsigned long long)s << 32) | (unsigned long long)(~idx);
            if (key > kl[7]) {
                unsigned long long c = key;
                #pragma unroll
                for (int i = 0; i < 8; ++i) {
                    unsigned long long old = kl[i];
                    bool gt = c > old;
                    kl[i] = gt ? c : old;
                    c = gt ? old : c;
                }
            }
        }
    }
    #pragma unroll
    for (int i = 0; i < 8; ++i) lkey[i * FNT + t] = kl[i];
    __syncthreads();

    int h = 0;
    int* out = cand_out + blockIdx.x * 64;
    for (int sel = 0; sel < 64; ++sel) {
        unsigned long long cnd = (h < 8) ? lkey[h * FNT + t] : 0ull;
        unsigned long long b = cnd;
        #pragma unroll
        for (int s2 = 1; s2 < 64; s2 <<= 1) {
            unsigned long long o = __shfl_xor(b, s2);
            if (o > b) b = o;
        }
        if ((t & 63) == 0) wkey[t >> 6] = b;
        __syncthreads();
        unsigned long long g = wkey[0];
        #pragma unroll
        for (int ww = 1; ww < FNT / 64; ++ww) {
            unsigned long long o = wkey[ww];
            if (o > g) g = o;
        }
        if (t == 0) out[sel] = (int)(~(unsigned)g);
        if (cnd == g) h++;
        __syncthreads();
    }
}

// ------- exact fp32 rescore of 64 candidates + exact top-32 -------
__global__ __launch_bounds__(256) void rescore_kernel(
    const float* __restrict__ Arows, const float* __restrict__ Brows,
    const int* __restrict__ cand, int K, int* __restrict__ idx_out)
{
    __shared__ float arow[4096];
    __shared__ unsigned long long exa[64];
    const int t = threadIdx.x;
    const int b = blockIdx.x;
    for (int i = t; i < (K >> 2); i += 256)
        ((float4*)arow)[i] = ((const float4*)(Arows + (size_t)b * K))[i];
    __syncthreads();
    const int w = t >> 6, lane = t & 63;
    for (int c = w; c < 64; c += 4) {
        int r = cand[b * 64 + c];
        const float4* bp = (const float4*)(Brows + (size_t)r * K);
        float s = 0.f;
        for (int q = lane; q < (K >> 2); q += 64) {
            float4 bv = bp[q];
            float4 av = ((float4*)arow)[q];
            s = fmaf(av.x, bv.x, fmaf(av.y, bv.y, fmaf(av.z, bv.z, fmaf(av.w, bv.w, s))));
        }
        #pragma unroll
        for (int sh = 1; sh < 64; sh <<= 1) s += __shfl_xor(s, sh);
        if (lane == 0) {
            unsigned fb = __float_as_uint(s);
            unsigned ss = (fb & 0x80000000u) ? ~fb : (fb | 0x80000000u);
            exa[c] = ((unsigned long long)ss << 32) | (unsigned long long)(~(unsigned)r);
        }
    }
    __syncthreads();
    if (t < 64) {
        unsigned long long key = exa[t];
        int* out = idx_out + b * TOPK;
        for (int sel = 0; sel < TOPK; ++sel) {
            unsigned long long g = key;
            #pragma unroll
            for (int sh = 1; sh < 64; sh <<= 1) {
                unsigned long long o = __shfl_xor(g, sh);
                if (o > g) g = o;
            }
            if (t == 0) out[sel] = (int)(~(unsigned)g);
            if (key == g) key = 0ull;
        }
    }
}

// ---- gather 32 rows of clique_encoder, sum, scale, l2-normalize (+bf16 copy) ----
__global__ __launch_bounds__(256) void gather_norm_kernel(
    const float* __restrict__ enc, const int* __restrict__ idx,
    float* __restrict__ p, short* __restrict__ p_bf)
{
    __shared__ int rows[TOPK];
    __shared__ float red[256];
    const int t = threadIdx.x;
    const int b = blockIdx.x;
    if (t < TOPK) rows[t] = idx[b * TOPK + t];
    __syncthreads();
    float4 acc[4] = {};
    for (int r = 0; r < TOPK; ++r) {
        const float* src = enc + (size_t)rows[r] * D + t * 16;
        #pragma unroll
        for (int q = 0; q < 4; ++q) {
            float4 v = *(const float4*)(src + q * 4);
            acc[q].x += v.x; acc[q].y += v.y; acc[q].z += v.z; acc[q].w += v.w;
        }
    }
    const float sc = 0.17677669529663687f; // 1/sqrt(32)
    float ss = 0.f;
    #pragma unroll
    for (int q = 0; q < 4; ++q) {
        acc[q].x *= sc; acc[q].y *= sc; acc[q].z *= sc; acc[q].w *= sc;
        ss += acc[q].x*acc[q].x + acc[q].y*acc[q].y + acc[q].z*acc[q].z + acc[q].w*acc[q].w;
    }
    red[t] = ss;
    __syncthreads();
    for (int s = 128; s > 0; s >>= 1) {
        if (t < s) red[t] += red[t + s];
        __syncthreads();
    }
    float rinv = 1.0f / fmaxf(sqrtf(red[0]), 1e-12f);
    float* dst = p + (size_t)b * D + t * 16;
    short4* dstb = (short4*)(p_bf + (size_t)b * D) + t * 4;
    #pragma unroll
    for (int q = 0; q < 4; ++q) {
        float4 o = {acc[q].x*rinv, acc[q].y*rinv, acc[q].z*rinv, acc[q].w*rinv};
        *(float4*)(dst + q * 4) = o;
        short4 ob = {f2bf(o.x), f2bf(o.y), f2bf(o.z), f2bf(o.w)};
        dstb[q] = ob;
    }
}

// -------- gather 32 rows of assoc_mem_value [.,32768], sum -> out --------
__global__ __launch_bounds__(256) void gather_out_kernel(
    const float* __restrict__ mem, const int* __restrict__ idx, float* __restrict__ out)
{
    __shared__ int rows[TOPK];
    const int t = threadIdx.x;
    const int b = blockIdx.y;
    const int chunk = blockIdx.x;
    if (t < TOPK) rows[t] = idx[b * TOPK + t];
    __syncthreads();
    const int off = chunk * 2048 + t * 8;
    float4 a0 = {}, a1 = {};
    for (int r = 0; r < TOPK; ++r) {
        const float* src = mem + (size_t)rows[r] * NVAL + off;
        float4 v0 = *(const float4*)(src);
        float4 v1 = *(const float4*)(src + 4);
        a0.x += v0.x; a0.y += v0.y; a0.z += v0.z; a0.w += v0.w;
        a1.x += v1.x; a1.y += v1.y; a1.z += v1.z; a1.w += v1.w;
    }
    float* dst = out + (size_t)b * NVAL + off;
    *(float4*)dst = a0;
    *(float4*)(dst + 4) = a1;
}

extern "C" void kernel_launch(void* const* d_in, const int* in_sizes, int n_in,
                              void* d_out, int out_size, void* d_ws, size_t ws_size,
                              hipStream_t stream) {
    const float* keys            = (const float*)d_in[0];
    const float* value_proj      = (const float*)d_in[1];
    const float* clique_encoder  = (const float*)d_in[2];
    const float* assoc_proj      = (const float*)d_in[3];
    const float* assoc_mem_value = (const float*)d_in[4];
    float* out = (float*)d_out;

    char* ws = (char*)d_ws;
    short* keysbf   = (short*)(ws);                    //   256 KB
    float* s1a      = (float*)(ws + 262144);           //    16 MB
    float* p        = (float*)(ws + 17039360);         //     2 MB
    short* p_bf     = (short*)(ws + 19136512);         //     1 MB
    float* part2    = (float*)(ws + 20185088);         //     8 MB
    float* s2a      = (float*)(ws + 28573696);         //     2 MB
    int*   cand1    = (int*)  (ws + 30670848);         //    32 KB
    int*   cand2    = (int*)  (ws + 30703616);         //    32 KB
    int*   idx1     = (int*)  (ws + 30736384);         //    16 KB
    int*   idx2     = (int*)  (ws + 30752768);         //    16 KB

    // 1) keys -> bf16
    cvt_bf16_kernel<<<128, 256, 0, stream>>>(keys, keysbf, 32768);
    // 2) approx scores1 = keysbf @ bf16(value_proj)^T
    gemm_bf16_kernel<<<dim3(512, 1), 256, 0, stream>>>(keysbf, value_proj, s1a, 1024, NVAL, 1024);
    // 3) top-64 candidates
    filter64_kernel<<<128, FNT, 0, stream>>>(s1a, NVAL, cand1);
    // 4) exact fp32 rescore -> top-32 idx1
    rescore_kernel<<<128, 256, 0, stream>>>(keys, value_proj, cand1, 1024, idx1);
    // 5) p = normalize(sum(clique_encoder[idx1]) / sqrt(32)), + bf16 copy
    gather_norm_kernel<<<128, 256, 0, stream>>>(clique_encoder, idx1, p, p_bf);
    // 6) approx scores2 = p_bf @ bf16(assoc_proj)^T, 4-way K-split
    gemm_bf16_kernel<<<dim3(64, 4), 256, 0, stream>>>(p_bf, assoc_proj, part2, 4096, D, 1024);
    // 7) reduce partials
    reduceS_kernel<<<512, 256, 0, stream>>>(part2, s2a, 131072, 4);
    // 8) top-64 candidates (exhaustive union for n=4096)
    filter64_kernel<<<128, FNT, 0, stream>>>(s2a, D, cand2);
    // 9) exact fp32 rescore -> top-32 idx2
    rescore_kernel<<<128, 256, 0, stream>>>(p, assoc_proj, cand2, 4096, idx2);
    // 10) out = sum(assoc_mem_value[idx2])
    gather_out_kernel<<<dim3(16, 128), 256, 0, stream>>>(assoc_mem_value, idx2, out);
}

// Round 4
// 445.203 us; speedup vs baseline: 2.8238x; 1.1929x over previous
//
#include <hip/hip_runtime.h>
#include <math.h>

#define TOPK 32
#define NVAL 32768
#define D 4096

typedef __attribute__((ext_vector_type(8))) short bf16x8;
typedef __attribute__((ext_vector_type(4))) float f32x4;

__device__ inline short f2bf(float x) {
    union { float f; unsigned u; } v; v.f = x;
    unsigned r = v.u + 0x7fffu + ((v.u >> 16) & 1u);  // RNE
    return (short)(r >> 16);
}

// ---------------- fp32 -> bf16 streaming convert ----------------
__global__ __launch_bounds__(256) void cvt_bf16_kernel(
    const float* __restrict__ in, short* __restrict__ out, int n4)
{
    int i = blockIdx.x * 256 + threadIdx.x;
    if (i < n4) {
        float4 v = ((const float4*)in)[i];
        short4 o = {f2bf(v.x), f2bf(v.y), f2bf(v.z), f2bf(v.w)};
        ((short4*)out)[i] = o;
    }
}

// ------- approx GEMM: C[128 x N] = A[128 x K](bf16) @ B[N x K](fp32->bf16)^T -------
// grid.x: N/64 (4 waves x 16 B-rows), grid.y: K-split. MFMA 16x16x32 bf16.
// 2-deep k-chunk prefetch (64B/lane in flight).
__global__ __launch_bounds__(256) void gemm_bf16_kernel(
    const short* __restrict__ Abf, const float* __restrict__ B,
    float* __restrict__ C, int K, int N, int klen)
{
    const int t = threadIdx.x;
    const int lane = t & 63;
    const int w = t >> 6;
    const int ntile = blockIdx.x * 64 + w * 16;
    const int k0 = blockIdx.y * klen;
    float* Cb = C + (size_t)blockIdx.y * 128 * N;

    const int kfrag = (lane >> 4) * 8;
    const float* bp = B + (size_t)(ntile + (lane & 15)) * K + kfrag;
    const short* ap = Abf + (size_t)(lane & 15) * K + kfrag;

    f32x4 acc[8];
    #pragma unroll
    for (int j = 0; j < 8; ++j) acc[j] = (f32x4){0.f, 0.f, 0.f, 0.f};

    float4 x0 = *(const float4*)(bp + k0);
    float4 x1 = *(const float4*)(bp + k0 + 4);
    float4 y0 = *(const float4*)(bp + k0 + 32);
    float4 y1 = *(const float4*)(bp + k0 + 36);
    for (int ks = k0; ks < k0 + klen; ks += 32) {
        bf16x8 af;
        af[0] = f2bf(x0.x); af[1] = f2bf(x0.y); af[2] = f2bf(x0.z); af[3] = f2bf(x0.w);
        af[4] = f2bf(x1.x); af[5] = f2bf(x1.y); af[6] = f2bf(x1.z); af[7] = f2bf(x1.w);
        x0 = y0; x1 = y1;
        if (ks + 64 < k0 + klen) {
            y0 = *(const float4*)(bp + ks + 64);
            y1 = *(const float4*)(bp + ks + 68);
        }
        #pragma unroll
        for (int j = 0; j < 8; ++j) {
            bf16x8 kf = *(const bf16x8*)(ap + (size_t)16 * K * j + ks);
            acc[j] = __builtin_amdgcn_mfma_f32_16x16x32_bf16(af, kf, acc[j], 0, 0, 0);
        }
    }
    const int crow0 = ntile + (lane >> 4) * 4;
    const int ccol = lane & 15;
    #pragma unroll
    for (int j = 0; j < 8; ++j) {
        float4 o = {acc[j][0], acc[j][1], acc[j][2], acc[j][3]};
        *(float4*)(Cb + (size_t)(16 * j + ccol) * N + crow0) = o;
    }
}

// ------------- reduce S K-split partials -> out -------------
__global__ __launch_bounds__(256) void reduceS_kernel(
    const float* __restrict__ part, float* __restrict__ out, int elems4, int S)
{
    int i = blockIdx.x * blockDim.x + threadIdx.x;
    if (i < elems4) {
        float4 s = {0.f, 0.f, 0.f, 0.f};
        for (int r = 0; r < S; ++r) {
            float4 v = *(const float4*)(part + (size_t)r * elems4 * 4 + (size_t)i * 4);
            s.x += v.x; s.y += v.y; s.z += v.z; s.w += v.w;
        }
        *(float4*)(out + (size_t)i * 4) = s;
    }
}

// ------------- top-64 candidate filter per row -------------
// key = (sortable_float_bits << 32) | ~idx  (value desc, index asc)
#define FNT 512
__global__ __launch_bounds__(FNT) void filter64_kernel(
    const float* __restrict__ scores, int n, int* __restrict__ cand_out)
{
    __shared__ unsigned long long lkey[8 * FNT];   // 32 KB
    __shared__ unsigned long long wkey[FNT / 64];
    const int t = threadIdx.x;
    const float* row = scores + (size_t)blockIdx.x * n;

    unsigned long long kl[8];
    #pragma unroll
    for (int i = 0; i < 8; ++i) kl[i] = 0ull;

    const int nvec = n >> 2;
    for (int base = t; base < nvec; base += FNT) {
        float4 x4 = *(const float4*)(row + base * 4);
        float xs[4] = {x4.x, x4.y, x4.z, x4.w};
        #pragma unroll
        for (int q = 0; q < 4; ++q) {
            unsigned fb = __float_as_uint(xs[q]);
            unsigned s = (fb & 0x80000000u) ? ~fb : (fb | 0x80000000u);
            unsigned idx = (unsigned)(base * 4 + q);
            unsigned long long key = ((unsigned long long)s << 32) | (unsigned long long)(~idx);
            if (key > kl[7]) {
                unsigned long long c = key;
                #pragma unroll
                for (int i = 0; i < 8; ++i) {
                    unsigned long long old = kl[i];
                    bool gt = c > old;
                    kl[i] = gt ? c : old;
                    c = gt ? old : c;
                }
            }
        }
    }
    #pragma unroll
    for (int i = 0; i < 8; ++i) lkey[i * FNT + t] = kl[i];
    __syncthreads();

    int h = 0;
    int* out = cand_out + blockIdx.x * 64;
    for (int sel = 0; sel < 64; ++sel) {
        unsigned long long cnd = (h < 8) ? lkey[h * FNT + t] : 0ull;
        unsigned long long b = cnd;
        #pragma unroll
        for (int s2 = 1; s2 < 64; s2 <<= 1) {
            unsigned long long o = __shfl_xor(b, s2);
            if (o > b) b = o;
        }
        if ((t & 63) == 0) wkey[t >> 6] = b;
        __syncthreads();
        unsigned long long g = wkey[0];
        #pragma unroll
        for (int ww = 1; ww < FNT / 64; ++ww) {
            unsigned long long o = wkey[ww];
            if (o > g) g = o;
        }
        if (t == 0) out[sel] = (int)(~(unsigned)g);
        if (cnd == g) h++;
        __syncthreads();
    }
}

// ------- exact fp32 rescore of candidate halves -> packed keys -------
__global__ __launch_bounds__(256) void rescore_part_kernel(
    const float* __restrict__ Arows, const float* __restrict__ Brows,
    const int* __restrict__ cand, int K, unsigned long long* __restrict__ keybuf)
{
    __shared__ float arow[4096];
    const int t = threadIdx.x;
    const int b = blockIdx.x;
    const int s = blockIdx.y;  // half 0/1
    for (int i = t; i < (K >> 2); i += 256)
        ((float4*)arow)[i] = ((const float4*)(Arows + (size_t)b * K))[i];
    __syncthreads();
    const int w = t >> 6, lane = t & 63;
    for (int c = s * 32 + w; c < s * 32 + 32; c += 4) {
        int r = cand[b * 64 + c];
        const float4* bp = (const float4*)(Brows + (size_t)r * K);
        float sum = 0.f;
        for (int q = lane; q < (K >> 2); q += 64) {
            float4 bv = bp[q];
            float4 av = ((float4*)arow)[q];
            sum = fmaf(av.x, bv.x, fmaf(av.y, bv.y, fmaf(av.z, bv.z, fmaf(av.w, bv.w, sum))));
        }
        #pragma unroll
        for (int sh = 1; sh < 64; sh <<= 1) sum += __shfl_xor(sum, sh);
        if (lane == 0) {
            unsigned fb = __float_as_uint(sum);
            unsigned ss = (fb & 0x80000000u) ? ~fb : (fb | 0x80000000u);
            keybuf[b * 64 + c] = ((unsigned long long)ss << 32) | (unsigned long long)(~(unsigned)r);
        }
    }
}

// ------- 1-wave exact top-32 from 64 packed keys -------
__global__ __launch_bounds__(64) void top32_keys_kernel(
    const unsigned long long* __restrict__ keybuf, int* __restrict__ idx_out)
{
    const int b = blockIdx.x, t = threadIdx.x;
    unsigned long long key = keybuf[b * 64 + t];
    int* out = idx_out + b * TOPK;
    for (int sel = 0; sel < TOPK; ++sel) {
        unsigned long long g = key;
        #pragma unroll
        for (int sh = 1; sh < 64; sh <<= 1) {
            unsigned long long o = __shfl_xor(g, sh);
            if (o > g) g = o;
        }
        if (t == 0) out[sel] = (int)(~(unsigned)g);
        if (key == g) key = 0ull;
    }
}

// ---- gather-sum 32 rows of clique_encoder (column half) + partial sumsq ----
__global__ __launch_bounds__(256) void gather_sum_kernel(
    const float* __restrict__ enc, const int* __restrict__ idx,
    float* __restrict__ p_raw, float* __restrict__ ssp)
{
    __shared__ int rows[TOPK];
    __shared__ float red[256];
    const int t = threadIdx.x;
    const int half = blockIdx.x;
    const int b = blockIdx.y;
    if (t < TOPK) rows[t] = idx[b * TOPK + t];
    __syncthreads();
    const int base = half * 2048 + t * 8;
    float4 a0 = {}, a1 = {};
    #pragma unroll 4
    for (int r = 0; r < TOPK; ++r) {
        const float* src = enc + (size_t)rows[r] * D + base;
        float4 v0 = *(const float4*)(src);
        float4 v1 = *(const float4*)(src + 4);
        a0.x += v0.x; a0.y += v0.y; a0.z += v0.z; a0.w += v0.w;
        a1.x += v1.x; a1.y += v1.y; a1.z += v1.z; a1.w += v1.w;
    }
    const float sc = 0.17677669529663687f; // 1/sqrt(32)
    a0.x *= sc; a0.y *= sc; a0.z *= sc; a0.w *= sc;
    a1.x *= sc; a1.y *= sc; a1.z *= sc; a1.w *= sc;
    float ss = a0.x*a0.x + a0.y*a0.y + a0.z*a0.z + a0.w*a0.w
             + a1.x*a1.x + a1.y*a1.y + a1.z*a1.z + a1.w*a1.w;
    red[t] = ss;
    __syncthreads();
    for (int s = 128; s > 0; s >>= 1) {
        if (t < s) red[t] += red[t + s];
        __syncthreads();
    }
    if (t == 0) ssp[b * 2 + half] = red[0];
    float* dst = p_raw + (size_t)b * D + base;
    *(float4*)dst = a0;
    *(float4*)(dst + 4) = a1;
}

// ---- finish normalize: p (fp32) + p_bf (bf16) ----
__global__ __launch_bounds__(256) void normalize_kernel(
    const float* __restrict__ p_raw, const float* __restrict__ ssp,
    float* __restrict__ p, short* __restrict__ p_bf)
{
    const int b = blockIdx.x, t = threadIdx.x;
    const float rinv = 1.0f / fmaxf(sqrtf(ssp[b * 2] + ssp[b * 2 + 1]), 1e-12f);
    for (int i = t; i < (D >> 2); i += 256) {
        float4 v = ((const float4*)(p_raw + (size_t)b * D))[i];
        float4 o = {v.x * rinv, v.y * rinv, v.z * rinv, v.w * rinv};
        ((float4*)(p + (size_t)b * D))[i] = o;
        short4 ob = {f2bf(o.x), f2bf(o.y), f2bf(o.z), f2bf(o.w)};
        ((short4*)(p_bf + (size_t)b * D))[i] = ob;
    }
}

// -------- gather 32 rows of assoc_mem_value, sum -> out --------
// grid.x = b (fast dim), grid.y = column chunk: co-scheduled blocks share the
// same chunk's distinct-row footprint (~21 MB) -> L2/L3 hits. Dynamic LDS
// (40KB, unused) throttles to ~3 blocks/CU so only ~6 chunk groups co-reside.
__global__ __launch_bounds__(256) void gather_out_kernel(
    const float* __restrict__ mem, const int* __restrict__ idx, float* __restrict__ out)
{
    extern __shared__ float throttle[];
    __shared__ int rows[TOPK];
    const int t = threadIdx.x;
    const int b = blockIdx.x;
    const int chunk = blockIdx.y;
    if (t < TOPK) rows[t] = idx[b * TOPK + t];
    __syncthreads();
    const int off = chunk * 2048 + t * 8;
    float4 a0 = {}, a1 = {};
    #pragma unroll 4
    for (int r = 0; r < TOPK; ++r) {
        const float* src = mem + (size_t)rows[r] * NVAL + off;
        float4 v0 = *(const float4*)(src);
        float4 v1 = *(const float4*)(src + 4);
        a0.x += v0.x; a0.y += v0.y; a0.z += v0.z; a0.w += v0.w;
        a1.x += v1.x; a1.y += v1.y; a1.z += v1.z; a1.w += v1.w;
    }
    if (rows[0] < 0) { throttle[t] = a0.x; out[0] = throttle[t + 1]; } // keep LDS alloc
    float* dst = out + (size_t)b * NVAL + off;
    *(float4*)dst = a0;
    *(float4*)(dst + 4) = a1;
}

extern "C" void kernel_launch(void* const* d_in, const int* in_sizes, int n_in,
                              void* d_out, int out_size, void* d_ws, size_t ws_size,
                              hipStream_t stream) {
    const float* keys            = (const float*)d_in[0];
    const float* value_proj      = (const float*)d_in[1];
    const float* clique_encoder  = (const float*)d_in[2];
    const float* assoc_proj      = (const float*)d_in[3];
    const float* assoc_mem_value = (const float*)d_in[4];
    float* out = (float*)d_out;

    char* ws = (char*)d_ws;
    short* keysbf = (short*)(ws);                           // 256 KB
    float* s1a    = (float*)(ws + 262144);                  // 16 MB
    float* p_raw  = (float*)(ws + 17039360);                // 2 MB
    float* p      = (float*)(ws + 19136512);                // 2 MB
    short* p_bf   = (short*)(ws + 21233664);                // 1 MB
    float* part2  = (float*)(ws + 22282240);                // 8 MB
    float* s2a    = (float*)(ws + 30670848);                // 2 MB
    int*   cand1  = (int*)  (ws + 32768000);                // 32 KB
    int*   cand2  = (int*)  (ws + 32800768);                // 32 KB
    int*   idx1   = (int*)  (ws + 32833536);                // 16 KB
    int*   idx2   = (int*)  (ws + 32849920);                // 16 KB
    unsigned long long* keyb1 = (unsigned long long*)(ws + 32866304);  // 64 KB
    unsigned long long* keyb2 = (unsigned long long*)(ws + 32931840);  // 64 KB
    float* ssp    = (float*)(ws + 32997376);                // 1 KB

    // 1) keys -> bf16
    cvt_bf16_kernel<<<128, 256, 0, stream>>>(keys, keysbf, 32768);
    // 2) approx scores1 = keysbf @ bf16(value_proj)^T
    gemm_bf16_kernel<<<dim3(512, 1), 256, 0, stream>>>(keysbf, value_proj, s1a, 1024, NVAL, 1024);
    // 3) top-64 candidates
    filter64_kernel<<<128, FNT, 0, stream>>>(s1a, NVAL, cand1);
    // 4) exact fp32 rescore (split 2) -> keys
    rescore_part_kernel<<<dim3(128, 2), 256, 0, stream>>>(keys, value_proj, cand1, 1024, keyb1);
    // 5) exact top-32 idx1
    top32_keys_kernel<<<128, 64, 0, stream>>>(keyb1, idx1);
    // 6) gather-sum clique_encoder rows (2-way column split)
    gather_sum_kernel<<<dim3(2, 128), 256, 0, stream>>>(clique_encoder, idx1, p_raw, ssp);
    // 7) normalize -> p, p_bf
    normalize_kernel<<<128, 256, 0, stream>>>(p_raw, ssp, p, p_bf);
    // 8) approx scores2 = p_bf @ bf16(assoc_proj)^T, 4-way K-split
    gemm_bf16_kernel<<<dim3(64, 4), 256, 0, stream>>>(p_bf, assoc_proj, part2, 4096, D, 1024);
    // 9) reduce partials
    reduceS_kernel<<<512, 256, 0, stream>>>(part2, s2a, 131072, 4);
    // 10) top-64 candidates (n=4096)
    filter64_kernel<<<128, FNT, 0, stream>>>(s2a, D, cand2);
    // 11) exact fp32 rescore (split 2) -> keys
    rescore_part_kernel<<<dim3(128, 2), 256, 0, stream>>>(p, assoc_proj, cand2, 4096, keyb2);
    // 12) exact top-32 idx2
    top32_keys_kernel<<<128, 64, 0, stream>>>(keyb2, idx2);
    // 13) out = sum(assoc_mem_value[idx2]) with L3-friendly ordering
    gather_out_kernel<<<dim3(128, 16), 256, 40960, stream>>>(assoc_mem_value, idx2, out);
}